// Round 10
// baseline (617.777 us; speedup 1.0000x reference)
//
#include <hip/hip_runtime.h>
#include <hip/hip_bf16.h>

#define N_NODES 50000
#define N_EDGES 800000
#define EMB_D 128
#define HID_D 256
#define OUT_D 128
#define NGRAPH 256

#define SCAN_B ((N_NODES + 256) / 256)   // 196 blocks covers N_NODES+1 slots
#define NSHARD 8

typedef __attribute__((ext_vector_type(8))) short short8;
typedef __attribute__((ext_vector_type(4))) float floatx4;
typedef __attribute__((ext_vector_type(2))) float floatx2;
typedef __attribute__((ext_vector_type(2))) unsigned short ushortx2;
typedef __attribute__((ext_vector_type(4))) unsigned short ushortx4;

__device__ inline void bf16split(float x, short& hi, short& lo) {
    __hip_bfloat16 h = __float2bfloat16(x);
    float r = x - __bfloat162float(h);
    __hip_bfloat16 l = __float2bfloat16(r);
    hi = *reinterpret_cast<short*>(&h);
    lo = *reinterpret_cast<short*>(&l);
}

__device__ inline unsigned short f2b(float f) {
    __hip_bfloat16 h = __float2bfloat16(f);
    return *reinterpret_cast<unsigned short*>(&h);
}

__device__ inline float b2f(unsigned short u) {
    union { unsigned int i; float f; } c;
    c.i = ((unsigned int)u) << 16;
    return c.f;
}

template<int VPL> struct UVec;
template<> struct UVec<2> { using T = ushortx2; using FV = floatx2; };
template<> struct UVec<4> { using T = ushortx4; using FV = floatx4; };

// ---------------- rank pass: 8-shard degree histogram + per-edge rank ----------------
__global__ void rank_kernel(const int* __restrict__ dst, int* __restrict__ deg8,
                            int* __restrict__ pos) {
    int e = blockIdx.x * blockDim.x + threadIdx.x;
    if (e >= N_EDGES) return;
    pos[e] = atomicAdd(&deg8[(size_t)(e & (NSHARD - 1)) * N_NODES + dst[e]], 1);
}

// ---------------- graph boundaries via binary search (batch is sorted) ----------------
__global__ void bstart_kernel(const int* __restrict__ batch, int* __restrict__ bstart) {
    int g = threadIdx.x;  // 0..256
    if (g > NGRAPH) return;
    int lo = 0, hi = N_NODES;
    while (lo < hi) {
        int mid = (lo + hi) >> 1;
        if (batch[mid] < g) lo = mid + 1;
        else hi = mid;
    }
    bstart[g] = lo;
}

// ---------------- scan phase A: merge shards, block sums, dinv, shard bases ----------------
__global__ void scan_a(const int* __restrict__ deg8, int* __restrict__ degt,
                       int* __restrict__ sb8, int* __restrict__ bsum,
                       float* __restrict__ dinv) {
    __shared__ int red[256];
    int t = threadIdx.x;
    int i = blockIdx.x * 256 + t;
    int tot = 0;
    if (i < N_NODES) {
        int run = 0;
#pragma unroll
        for (int k = 0; k < NSHARD; ++k) {
            sb8[(size_t)k * N_NODES + i] = run;
            run += deg8[(size_t)k * N_NODES + i];
        }
        tot = run;
        degt[i] = tot;
        dinv[i] = rsqrtf((float)tot + 1.0f);
    }
    red[t] = tot;
    __syncthreads();
    for (int off = 128; off > 0; off >>= 1) {
        if (t < off) red[t] += red[t + off];
        __syncthreads();
    }
    if (t == 0) bsum[blockIdx.x] = red[0];
}

// ---------------- phase B: exclusive scan of block sums (1 block) ----------------
__global__ void scan_b(const int* __restrict__ bsum, int* __restrict__ boff) {
    __shared__ int s[256];
    int t = threadIdx.x;
    s[t] = (t < SCAN_B) ? bsum[t] : 0;
    __syncthreads();
    for (int off = 1; off < 256; off <<= 1) {
        int v = (t >= off) ? s[t - off] : 0;
        __syncthreads();
        s[t] += v;
        __syncthreads();
    }
    if (t < SCAN_B) boff[t] = (t == 0) ? 0 : s[t - 1];
}

// ---------------- phase C: in-block scan + offset -> row_start ----------------
__global__ void scan_c(const int* __restrict__ degt, const int* __restrict__ boff,
                       int* __restrict__ row_start) {
    __shared__ int s[256];
    int t = threadIdx.x;
    int i = blockIdx.x * 256 + t;
    int v = (i < N_NODES) ? degt[i] : 0;
    s[t] = v;
    __syncthreads();
    for (int off = 1; off < 256; off <<= 1) {
        int x = (t >= off) ? s[t - off] : 0;
        __syncthreads();
        s[t] += x;
        __syncthreads();
    }
    int excl = s[t] - v;
    int rs = boff[blockIdx.x] + excl;
    if (i <= N_NODES) row_start[i] = rs;
}

// ---------------- atomic-free CSR scatter (src only; norm folded into rows) ----------
__global__ void scatter_kernel(const int* __restrict__ src, const int* __restrict__ dst,
                               const int* __restrict__ pos, const int* __restrict__ row_start,
                               const int* __restrict__ sb8,
                               int* __restrict__ csr_src) {
    int e = blockIdx.x * blockDim.x + threadIdx.x;
    if (e >= N_EDGES) return;
    int d = dst[e];
    int slot = row_start[d] + sb8[(size_t)(e & (NSHARD - 1)) * N_NODES + d] + pos[e];
    csr_src[slot] = src[e];
}

// ---------------- embedding gather -> pre-scaled bf16 rows: E'[i] = dinv[i]*emb ----
__global__ void gather_bf16(const int* __restrict__ ids, const float* __restrict__ embed,
                            const float* __restrict__ dinv, unsigned short* __restrict__ X0) {
    int idx = blockIdx.x * blockDim.x + threadIdx.x;  // one floatx4 each
    const int V = EMB_D / 4;
    if (idx >= N_NODES * V) return;
    int row = idx / V, c = idx % V;
    floatx4 v = ((const floatx4*)embed)[(size_t)ids[row] * V + c];
    float s = dinv[row];
    ushortx4 u;
    u[0] = f2b(v[0] * s); u[1] = f2b(v[1] * s); u[2] = f2b(v[2] * s); u[3] = f2b(v[3] * s);
    __builtin_nontemporal_store(u, (ushortx4*)X0 + idx);
}

// ---------------- fused aggregation over pre-scaled bf16 rows ----------------
// OUT[i] = dinv[i]*(sum_e H'[src_e] + H'[i]) (+b) (+Xres) (relu),  H'[x]=dinv[x]*h[x]
// One wave per node, full row per wave (8 B/lane loads at D=256).
template<int D, bool HASB, bool RES, bool RELU>
__global__ __launch_bounds__(256) void agg_node(
        const int* __restrict__ row_start, const int* __restrict__ csr_src,
        const float* __restrict__ dinv,
        const unsigned short* __restrict__ Hs, const float* __restrict__ b,
        float* __restrict__ OUT) {
    constexpr int VPL = D / 64;
    using UV = typename UVec<VPL>::T;
    using FV = typename UVec<VPL>::FV;
    int wave = threadIdx.x >> 6, lane = threadIdx.x & 63;
    int i = blockIdx.x * 4 + wave;
    if (i >= N_NODES) return;
    const int off = lane * VPL;
    float acc0[VPL], acc1[VPL];
#pragma unroll
    for (int v = 0; v < VPL; ++v) { acc0[v] = 0.f; acc1[v] = 0.f; }
    int e0 = row_start[i], e1 = row_start[i + 1];
    int e = e0;
    for (; e + 3 < e1; e += 4) {
        int s0 = __builtin_nontemporal_load(csr_src + e);
        int s1 = __builtin_nontemporal_load(csr_src + e + 1);
        int s2 = __builtin_nontemporal_load(csr_src + e + 2);
        int s3 = __builtin_nontemporal_load(csr_src + e + 3);
        UV u0 = *(const UV*)(Hs + (size_t)s0 * D + off);
        UV u1 = *(const UV*)(Hs + (size_t)s1 * D + off);
        UV u2 = *(const UV*)(Hs + (size_t)s2 * D + off);
        UV u3 = *(const UV*)(Hs + (size_t)s3 * D + off);
#pragma unroll
        for (int v = 0; v < VPL; ++v) acc0[v] += b2f(u0[v]);
#pragma unroll
        for (int v = 0; v < VPL; ++v) acc1[v] += b2f(u1[v]);
#pragma unroll
        for (int v = 0; v < VPL; ++v) acc0[v] += b2f(u2[v]);
#pragma unroll
        for (int v = 0; v < VPL; ++v) acc1[v] += b2f(u3[v]);
    }
    for (; e < e1; ++e) {
        int s0 = __builtin_nontemporal_load(csr_src + e);
        UV u0 = *(const UV*)(Hs + (size_t)s0 * D + off);
#pragma unroll
        for (int v = 0; v < VPL; ++v) acc0[v] += b2f(u0[v]);
    }
    UV us = *(const UV*)(Hs + (size_t)i * D + off);
    float di = dinv[i];
    float* xp = OUT + (size_t)i * D + off;
    FV res;
    if (RES) res = *(const FV*)xp;
    FV outv;
#pragma unroll
    for (int v = 0; v < VPL; ++v) {
        float val = (acc0[v] + acc1[v] + b2f(us[v])) * di;
        if (HASB) val += b[off + v];
        if (RES)  val += res[v];
        if (RELU) val = fmaxf(val, 0.f);
        outv[v] = val;
    }
    __builtin_nontemporal_store(outv, (FV*)xp);
}

// ---------------- W pre-split into B-fragment-major bf16 hi/lo ----------------
template<int K, int D>
__global__ void wsplit_k(const float* __restrict__ W, short* __restrict__ hi,
                         short* __restrict__ lo) {
    int idx = blockIdx.x * blockDim.x + threadIdx.x;
    if (idx >= K * D) return;
    int j = idx & 7;
    int l = (idx >> 3) & 63;
    int rest = idx >> 9;
    int kb = rest % (K / 32);
    int t = rest / (K / 32);
    int k = kb * 32 + (l >> 4) * 8 + j;
    int ncol = t * 16 + (l & 15);
    bf16split(W[(size_t)k * D + ncol], hi[idx], lo[idx]);
}

// ---------------- MFMA GEMM: Hout[N,D] = A[N,K] @ W[K,D] (+bias)(+relu)(row-scale) ----
template<int K, int D, bool BIAS, bool RELU, bool OUTBF, bool SCALE>
__global__ __launch_bounds__(256) void gemm_mfma(
        const float* __restrict__ A, const short* __restrict__ Whi,
        const short* __restrict__ Wlo, const float* __restrict__ b,
        const float* __restrict__ sc, void* __restrict__ Hout, int n) {
    constexpr int LDK = K + 8;
    constexpr int NT = D / 64;
    constexpr int KB = K / 32;
    __shared__ short Ahi[64 * LDK];
    __shared__ short Alo[64 * LDK];

    int row0 = blockIdx.x * 64;
    constexpr int NF4 = 64 * (K / 4);
    for (int idx = threadIdx.x; idx < NF4; idx += 256) {
        int r = idx / (K / 4), c4 = idx % (K / 4);
        floatx4 v = (floatx4){0.f, 0.f, 0.f, 0.f};
        if (row0 + r < n) v = __builtin_nontemporal_load((const floatx4*)A + (size_t)(row0 + r) * (K / 4) + c4);
        int base = r * LDK + c4 * 4;
        bf16split(v[0], Ahi[base + 0], Alo[base + 0]);
        bf16split(v[1], Ahi[base + 1], Alo[base + 1]);
        bf16split(v[2], Ahi[base + 2], Alo[base + 2]);
        bf16split(v[3], Ahi[base + 3], Alo[base + 3]);
    }
    __syncthreads();

    int wave = threadIdx.x >> 6, lane = threadIdx.x & 63;
    int quad = lane >> 4, lane15 = lane & 15;

    floatx4 acc[4][NT];
#pragma unroll
    for (int mt = 0; mt < 4; ++mt)
#pragma unroll
        for (int nt = 0; nt < NT; ++nt)
            acc[mt][nt] = (floatx4){0.f, 0.f, 0.f, 0.f};

#pragma unroll
    for (int kb = 0; kb < KB; ++kb) {
        short8 ah[4], al[4];
#pragma unroll
        for (int mt = 0; mt < 4; ++mt) {
            int addr = (mt * 16 + lane15) * LDK + kb * 32 + quad * 8;
            ah[mt] = *(const short8*)&Ahi[addr];
            al[mt] = *(const short8*)&Alo[addr];
        }
        short8 bh[NT], bl[NT];
#pragma unroll
        for (int nt = 0; nt < NT; ++nt) {
            int t = wave * NT + nt;
            size_t fb = ((size_t)(t * KB + kb) * 64 + lane) * 8;
            bh[nt] = *(const short8*)&Whi[fb];
            bl[nt] = *(const short8*)&Wlo[fb];
        }
#pragma unroll
        for (int mt = 0; mt < 4; ++mt)
#pragma unroll
            for (int nt = 0; nt < NT; ++nt) {
                acc[mt][nt] = __builtin_amdgcn_mfma_f32_16x16x32_bf16(ah[mt], bh[nt], acc[mt][nt], 0, 0, 0);
                acc[mt][nt] = __builtin_amdgcn_mfma_f32_16x16x32_bf16(ah[mt], bl[nt], acc[mt][nt], 0, 0, 0);
                acc[mt][nt] = __builtin_amdgcn_mfma_f32_16x16x32_bf16(al[mt], bh[nt], acc[mt][nt], 0, 0, 0);
            }
    }

#pragma unroll
    for (int mt = 0; mt < 4; ++mt) {
#pragma unroll
        for (int nt = 0; nt < NT; ++nt) {
            int col = wave * (NT * 16) + nt * 16 + lane15;
            float bj = BIAS ? b[col] : 0.f;
#pragma unroll
            for (int reg = 0; reg < 4; ++reg) {
                int row = row0 + mt * 16 + quad * 4 + reg;
                if (row < n) {
                    float v = acc[mt][nt][reg] + bj;
                    if (RELU) v = fmaxf(v, 0.f);
                    if (SCALE) v *= sc[row];
                    if (OUTBF) __builtin_nontemporal_store(f2b(v), (unsigned short*)Hout + (size_t)row * D + col);
                    else       __builtin_nontemporal_store(v, (float*)Hout + (size_t)row * D + col);
                }
            }
        }
    }
}

// ---------------- readout: one block per graph, atomic-free mean ----------------
__global__ void graph_mean(const int* __restrict__ bstart, const float* __restrict__ X,
                           float* __restrict__ out) {
    int g = blockIdx.x;
    int r0 = bstart[g], r1 = bstart[g + 1];
    int col = threadIdx.x & 127, rr = threadIdx.x >> 7;  // 2 rows in flight
    float acc = 0.f;
    for (int r = r0 + rr; r < r1; r += 2)
        acc += __builtin_nontemporal_load(X + (size_t)r * OUT_D + col);
    __shared__ float sh[128];
    if (rr == 1) sh[col] = acc;
    __syncthreads();
    if (rr == 0) {
        float tot = acc + sh[col];
        int c = r1 - r0;
        out[(size_t)g * OUT_D + col] = tot / (float)(c > 0 ? c : 1);
    }
}

extern "C" void kernel_launch(void* const* d_in, const int* in_sizes, int n_in,
                              void* d_out, int out_size, void* d_ws, size_t ws_size,
                              hipStream_t stream) {
    const int* node_ids = (const int*)d_in[0];
    const int* edge_index = (const int*)d_in[1];
    const int* batch = (const int*)d_in[2];
    const float* embed = (const float*)d_in[3];
    const float* W_in  = (const float*)d_in[4];
    const float* b_in  = (const float*)d_in[5];
    const float* W_h1  = (const float*)d_in[6];
    const float* b_h1  = (const float*)d_in[7];
    const float* W_h2  = (const float*)d_in[8];
    const float* b_h2  = (const float*)d_in[9];
    const float* W_out = (const float*)d_in[10];
    const float* b_out = (const float*)d_in[11];
    float* out = (float*)d_out;

    const int* src = edge_index;
    const int* dst = edge_index + N_EDGES;

    char* w = (char*)d_ws;
    size_t o = 0;
    auto alloc = [&](size_t bytes) -> void* {
        void* p = w + o;
        o = (o + bytes + 255) & ~(size_t)255;
        return p;
    };
    int*   deg8     = (int*)alloc((size_t)NSHARD * N_NODES * sizeof(int));
    int*   sb8      = (int*)alloc((size_t)NSHARD * N_NODES * sizeof(int));
    int*   degt     = (int*)alloc((size_t)N_NODES * sizeof(int));
    int*   pos      = (int*)alloc((size_t)N_EDGES * sizeof(int));
    float* dinv     = (float*)alloc((size_t)N_NODES * sizeof(float));
    int*   bstart   = (int*)alloc((size_t)(NGRAPH + 1) * sizeof(int));
    int*   row_start= (int*)alloc((size_t)(N_NODES + 1) * sizeof(int));
    int*   bsum     = (int*)alloc((size_t)SCAN_B * sizeof(int));
    int*   boff     = (int*)alloc((size_t)SCAN_B * sizeof(int));
    int*   csr_src  = (int*)alloc((size_t)N_EDGES * sizeof(int));
    float* X        = (float*)alloc((size_t)N_NODES * HID_D * sizeof(float));     // fp32 residual
    unsigned short* H16 = (unsigned short*)alloc((size_t)N_NODES * HID_D * sizeof(short)); // pre-scaled bf16
    float* A1       = (float*)alloc((size_t)N_NODES * 128 * sizeof(float));       // fp32 agg out (128-d)
    short* Whi_in   = (short*)alloc((size_t)EMB_D * HID_D * sizeof(short));
    short* Wlo_in   = (short*)alloc((size_t)EMB_D * HID_D * sizeof(short));
    short* Whi_h1   = (short*)alloc((size_t)HID_D * HID_D * sizeof(short));
    short* Wlo_h1   = (short*)alloc((size_t)HID_D * HID_D * sizeof(short));
    short* Whi_h2   = (short*)alloc((size_t)HID_D * HID_D * sizeof(short));
    short* Wlo_h2   = (short*)alloc((size_t)HID_D * HID_D * sizeof(short));
    short* Whi_out  = (short*)alloc((size_t)HID_D * OUT_D * sizeof(short));
    short* Wlo_out  = (short*)alloc((size_t)HID_D * OUT_D * sizeof(short));
    unsigned short* E16 = H16;               // layer-1 bf16 embeddings alias
    unsigned short* H4  = H16;               // layer-4 bf16 GEMM out [N,128] alias
    (void)ws_size;

    hipMemsetAsync(deg8, 0, (size_t)NSHARD * N_NODES * sizeof(int), stream);

    rank_kernel<<<(N_EDGES + 255) / 256, 256, 0, stream>>>(dst, deg8, pos);
    bstart_kernel<<<1, 512, 0, stream>>>(batch, bstart);
    scan_a<<<SCAN_B, 256, 0, stream>>>(deg8, degt, sb8, bsum, dinv);
    scan_b<<<1, 256, 0, stream>>>(bsum, boff);
    scan_c<<<SCAN_B, 256, 0, stream>>>(degt, boff, row_start);
    scatter_kernel<<<(N_EDGES + 255) / 256, 256, 0, stream>>>(src, dst, pos, row_start,
                                                              sb8, csr_src);

    wsplit_k<EMB_D, HID_D><<<(EMB_D * HID_D + 255) / 256, 256, 0, stream>>>(W_in, Whi_in, Wlo_in);
    wsplit_k<HID_D, HID_D><<<(HID_D * HID_D + 255) / 256, 256, 0, stream>>>(W_h1, Whi_h1, Wlo_h1);
    wsplit_k<HID_D, HID_D><<<(HID_D * HID_D + 255) / 256, 256, 0, stream>>>(W_h2, Whi_h2, Wlo_h2);
    wsplit_k<HID_D, OUT_D><<<(HID_D * OUT_D + 255) / 256, 256, 0, stream>>>(W_out, Whi_out, Wlo_out);

    const int gemm_grid = (N_NODES + 63) / 64;
    const int agg_grid = (N_NODES + 3) / 4;

    // ---- Layer 1: gather emb (pre-scaled bf16), agg at 128, GEMM 128->256 +bias+relu ----
    gather_bf16<<<(N_NODES * (EMB_D / 4) + 255) / 256, 256, 0, stream>>>(node_ids, embed, dinv, E16);
    agg_node<128, false, false, false><<<agg_grid, 256, 0, stream>>>(
        row_start, csr_src, dinv, E16, nullptr, A1);
    gemm_mfma<128, 256, true, true, false, false><<<gemm_grid, 256, 0, stream>>>(
        A1, Whi_in, Wlo_in, b_in, nullptr, X, N_NODES);

    // ---- Layer 2: GEMM 256->256 (bf16 out, row-scaled), fused agg+self+bias+res+relu ----
    gemm_mfma<256, 256, false, false, true, true><<<gemm_grid, 256, 0, stream>>>(
        X, Whi_h1, Wlo_h1, nullptr, dinv, H16, N_NODES);
    agg_node<256, true, true, true><<<agg_grid, 256, 0, stream>>>(
        row_start, csr_src, dinv, H16, b_h1, X);

    // ---- Layer 3: same ----
    gemm_mfma<256, 256, false, false, true, true><<<gemm_grid, 256, 0, stream>>>(
        X, Whi_h2, Wlo_h2, nullptr, dinv, H16, N_NODES);
    agg_node<256, true, true, true><<<agg_grid, 256, 0, stream>>>(
        row_start, csr_src, dinv, H16, b_h2, X);

    // ---- Layer 4: GEMM 256->128 (bf16 out, row-scaled), agg at 128 +bias ----
    gemm_mfma<256, 128, false, false, true, true><<<gemm_grid, 256, 0, stream>>>(
        X, Whi_out, Wlo_out, nullptr, dinv, H4, N_NODES);
    agg_node<128, true, false, false><<<agg_grid, 256, 0, stream>>>(
        row_start, csr_src, dinv, H4, b_out, A1);

    // ---- readout: atomic-free per-graph mean (batch sorted) ----
    graph_mean<<<NGRAPH, 256, 0, stream>>>(bstart, A1, out);
}

// Round 11
// 568.229 us; speedup vs baseline: 1.0872x; 1.0872x over previous
//
#include <hip/hip_runtime.h>
#include <hip/hip_bf16.h>

#define N_NODES 50000
#define N_EDGES 800000
#define EMB_D 128
#define HID_D 256
#define OUT_D 128
#define NGRAPH 256

#define SCAN_B ((N_NODES + 256) / 256)   // 196 blocks covers N_NODES+1 slots
#define NSHARD 8

typedef __attribute__((ext_vector_type(8))) short short8;
typedef __attribute__((ext_vector_type(4))) float floatx4;
typedef __attribute__((ext_vector_type(2))) float floatx2;
typedef __attribute__((ext_vector_type(2))) unsigned short ushortx2;
typedef __attribute__((ext_vector_type(4))) unsigned short ushortx4;

__device__ inline void bf16split(float x, short& hi, short& lo) {
    __hip_bfloat16 h = __float2bfloat16(x);
    float r = x - __bfloat162float(h);
    __hip_bfloat16 l = __float2bfloat16(r);
    hi = *reinterpret_cast<short*>(&h);
    lo = *reinterpret_cast<short*>(&l);
}

__device__ inline unsigned short f2b(float f) {
    __hip_bfloat16 h = __float2bfloat16(f);
    return *reinterpret_cast<unsigned short*>(&h);
}

__device__ inline float b2f(unsigned short u) {
    union { unsigned int i; float f; } c;
    c.i = ((unsigned int)u) << 16;
    return c.f;
}

template<int VPL> struct UVec;
template<> struct UVec<2> { using T = ushortx2; using FV = floatx2; };
template<> struct UVec<4> { using T = ushortx4; using FV = floatx4; };

// ---------------- rank pass: 8-shard degree histogram + per-edge rank ----------------
__global__ void rank_kernel(const int* __restrict__ dst, int* __restrict__ deg8,
                            int* __restrict__ pos) {
    int e = blockIdx.x * blockDim.x + threadIdx.x;
    if (e >= N_EDGES) return;
    pos[e] = atomicAdd(&deg8[(size_t)(e & (NSHARD - 1)) * N_NODES + dst[e]], 1);
}

// ---------------- graph boundaries via binary search (batch is sorted) ----------------
__global__ void bstart_kernel(const int* __restrict__ batch, int* __restrict__ bstart) {
    int g = threadIdx.x;  // 0..256
    if (g > NGRAPH) return;
    int lo = 0, hi = N_NODES;
    while (lo < hi) {
        int mid = (lo + hi) >> 1;
        if (batch[mid] < g) lo = mid + 1;
        else hi = mid;
    }
    bstart[g] = lo;
}

// ---------------- scan phase A: merge shards, block sums, dinv, shard bases ----------------
__global__ void scan_a(const int* __restrict__ deg8, int* __restrict__ degt,
                       int* __restrict__ sb8, int* __restrict__ bsum,
                       float* __restrict__ dinv) {
    __shared__ int red[256];
    int t = threadIdx.x;
    int i = blockIdx.x * 256 + t;
    int tot = 0;
    if (i < N_NODES) {
        int run = 0;
#pragma unroll
        for (int k = 0; k < NSHARD; ++k) {
            sb8[(size_t)k * N_NODES + i] = run;
            run += deg8[(size_t)k * N_NODES + i];
        }
        tot = run;
        degt[i] = tot;
        dinv[i] = rsqrtf((float)tot + 1.0f);
    }
    red[t] = tot;
    __syncthreads();
    for (int off = 128; off > 0; off >>= 1) {
        if (t < off) red[t] += red[t + off];
        __syncthreads();
    }
    if (t == 0) bsum[blockIdx.x] = red[0];
}

// ---------------- phase B: exclusive scan of block sums (1 block) ----------------
__global__ void scan_b(const int* __restrict__ bsum, int* __restrict__ boff) {
    __shared__ int s[256];
    int t = threadIdx.x;
    s[t] = (t < SCAN_B) ? bsum[t] : 0;
    __syncthreads();
    for (int off = 1; off < 256; off <<= 1) {
        int v = (t >= off) ? s[t - off] : 0;
        __syncthreads();
        s[t] += v;
        __syncthreads();
    }
    if (t < SCAN_B) boff[t] = (t == 0) ? 0 : s[t - 1];
}

// ---------------- phase C: in-block scan + offset -> row_start ----------------
__global__ void scan_c(const int* __restrict__ degt, const int* __restrict__ boff,
                       int* __restrict__ row_start) {
    __shared__ int s[256];
    int t = threadIdx.x;
    int i = blockIdx.x * 256 + t;
    int v = (i < N_NODES) ? degt[i] : 0;
    s[t] = v;
    __syncthreads();
    for (int off = 1; off < 256; off <<= 1) {
        int x = (t >= off) ? s[t - off] : 0;
        __syncthreads();
        s[t] += x;
        __syncthreads();
    }
    int excl = s[t] - v;
    int rs = boff[blockIdx.x] + excl;
    if (i <= N_NODES) row_start[i] = rs;
}

// ---------------- atomic-free CSR scatter (src only; norm folded into rows) ----------
__global__ void scatter_kernel(const int* __restrict__ src, const int* __restrict__ dst,
                               const int* __restrict__ pos, const int* __restrict__ row_start,
                               const int* __restrict__ sb8,
                               int* __restrict__ csr_src) {
    int e = blockIdx.x * blockDim.x + threadIdx.x;
    if (e >= N_EDGES) return;
    int d = dst[e];
    int slot = row_start[d] + sb8[(size_t)(e & (NSHARD - 1)) * N_NODES + d] + pos[e];
    csr_src[slot] = src[e];
}

// ---------------- embedding gather -> pre-scaled bf16 rows: E'[i] = dinv[i]*emb ----
__global__ void gather_bf16(const int* __restrict__ ids, const float* __restrict__ embed,
                            const float* __restrict__ dinv, unsigned short* __restrict__ X0) {
    int idx = blockIdx.x * blockDim.x + threadIdx.x;  // one floatx4 each
    const int V = EMB_D / 4;
    if (idx >= N_NODES * V) return;
    int row = idx / V, c = idx % V;
    floatx4 v = ((const floatx4*)embed)[(size_t)ids[row] * V + c];
    float s = dinv[row];
    ushortx4 u;
    u[0] = f2b(v[0] * s); u[1] = f2b(v[1] * s); u[2] = f2b(v[2] * s); u[3] = f2b(v[3] * s);
    ((ushortx4*)X0)[idx] = u;
}

// ---------------- fused aggregation over pre-scaled bf16 rows ----------------
// OUT[i] = dinv[i]*(sum_e H'[src_e] + H'[i]) (+b) (+Xres) (relu),  H'[x]=dinv[x]*h[x]
// One wave per node, full row per wave (8 B/lane loads at D=256).
template<int D, bool HASB, bool RES, bool RELU>
__global__ __launch_bounds__(256) void agg_node(
        const int* __restrict__ row_start, const int* __restrict__ csr_src,
        const float* __restrict__ dinv,
        const unsigned short* __restrict__ Hs, const float* __restrict__ b,
        float* __restrict__ OUT) {
    constexpr int VPL = D / 64;
    using UV = typename UVec<VPL>::T;
    using FV = typename UVec<VPL>::FV;
    int wave = threadIdx.x >> 6, lane = threadIdx.x & 63;
    int i = blockIdx.x * 4 + wave;
    if (i >= N_NODES) return;
    const int off = lane * VPL;
    float acc0[VPL], acc1[VPL];
#pragma unroll
    for (int v = 0; v < VPL; ++v) { acc0[v] = 0.f; acc1[v] = 0.f; }
    int e0 = row_start[i], e1 = row_start[i + 1];
    int e = e0;
    for (; e + 3 < e1; e += 4) {
        int s0 = csr_src[e], s1 = csr_src[e + 1], s2 = csr_src[e + 2], s3 = csr_src[e + 3];
        UV u0 = *(const UV*)(Hs + (size_t)s0 * D + off);
        UV u1 = *(const UV*)(Hs + (size_t)s1 * D + off);
        UV u2 = *(const UV*)(Hs + (size_t)s2 * D + off);
        UV u3 = *(const UV*)(Hs + (size_t)s3 * D + off);
#pragma unroll
        for (int v = 0; v < VPL; ++v) acc0[v] += b2f(u0[v]);
#pragma unroll
        for (int v = 0; v < VPL; ++v) acc1[v] += b2f(u1[v]);
#pragma unroll
        for (int v = 0; v < VPL; ++v) acc0[v] += b2f(u2[v]);
#pragma unroll
        for (int v = 0; v < VPL; ++v) acc1[v] += b2f(u3[v]);
    }
    for (; e < e1; ++e) {
        int s0 = csr_src[e];
        UV u0 = *(const UV*)(Hs + (size_t)s0 * D + off);
#pragma unroll
        for (int v = 0; v < VPL; ++v) acc0[v] += b2f(u0[v]);
    }
    UV us = *(const UV*)(Hs + (size_t)i * D + off);
    float di = dinv[i];
    float* xp = OUT + (size_t)i * D + off;
    FV res;
    if (RES) res = *(const FV*)xp;
    FV outv;
#pragma unroll
    for (int v = 0; v < VPL; ++v) {
        float val = (acc0[v] + acc1[v] + b2f(us[v])) * di;
        if (HASB) val += b[off + v];
        if (RES)  val += res[v];
        if (RELU) val = fmaxf(val, 0.f);
        outv[v] = val;
    }
    *(FV*)xp = outv;
}

// ---------------- W pre-split into B-fragment-major bf16 hi/lo ----------------
template<int K, int D>
__global__ void wsplit_k(const float* __restrict__ W, short* __restrict__ hi,
                         short* __restrict__ lo) {
    int idx = blockIdx.x * blockDim.x + threadIdx.x;
    if (idx >= K * D) return;
    int j = idx & 7;
    int l = (idx >> 3) & 63;
    int rest = idx >> 9;
    int kb = rest % (K / 32);
    int t = rest / (K / 32);
    int k = kb * 32 + (l >> 4) * 8 + j;
    int ncol = t * 16 + (l & 15);
    bf16split(W[(size_t)k * D + ncol], hi[idx], lo[idx]);
}

// ---------------- MFMA GEMM: Hout[N,D] = A[N,K] @ W[K,D] (+bias)(+relu)(row-scale) ----
// Two-phase K-loop (BK=128) reusing one half-size LDS buffer: 34.8 KB -> 4 blocks/CU.
template<int K, int D, bool BIAS, bool RELU, bool OUTBF, bool SCALE>
__global__ __launch_bounds__(256) void gemm_mfma(
        const float* __restrict__ A, const short* __restrict__ Whi,
        const short* __restrict__ Wlo, const float* __restrict__ b,
        const float* __restrict__ sc, void* __restrict__ Hout, int n) {
    constexpr int BK = 128;            // K per phase
    constexpr int LDK = BK + 8;        // padded LDS row stride
    constexpr int PH = K / BK;         // 1 or 2 phases
    constexpr int NT = D / 64;         // n-tiles per wave
    constexpr int KB = K / 32;         // total MFMA K-steps (B-frag index)
    __shared__ short Ahi[64 * LDK];
    __shared__ short Alo[64 * LDK];

    int row0 = blockIdx.x * 64;
    int wave = threadIdx.x >> 6, lane = threadIdx.x & 63;
    int quad = lane >> 4, lane15 = lane & 15;

    floatx4 acc[4][NT];
#pragma unroll
    for (int mt = 0; mt < 4; ++mt)
#pragma unroll
        for (int nt = 0; nt < NT; ++nt)
            acc[mt][nt] = (floatx4){0.f, 0.f, 0.f, 0.f};

#pragma unroll
    for (int ph = 0; ph < PH; ++ph) {
        if (ph) __syncthreads();       // protect LDS before re-staging
        // ---- stage 64 rows x BK cols of A (fp32 -> bf16 hi/lo) ----
        constexpr int NF4 = 64 * (BK / 4);
        for (int idx = threadIdx.x; idx < NF4; idx += 256) {
            int r = idx / (BK / 4), c4 = idx % (BK / 4);
            floatx4 v = (floatx4){0.f, 0.f, 0.f, 0.f};
            if (row0 + r < n)
                v = ((const floatx4*)A)[(size_t)(row0 + r) * (K / 4) + ph * (BK / 4) + c4];
            int base = r * LDK + c4 * 4;
            bf16split(v[0], Ahi[base + 0], Alo[base + 0]);
            bf16split(v[1], Ahi[base + 1], Alo[base + 1]);
            bf16split(v[2], Ahi[base + 2], Alo[base + 2]);
            bf16split(v[3], Ahi[base + 3], Alo[base + 3]);
        }
        __syncthreads();

#pragma unroll
        for (int kb = 0; kb < BK / 32; ++kb) {
            int kbg = ph * (BK / 32) + kb;   // global K-step for B frags
            short8 ah[4], al[4];
#pragma unroll
            for (int mt = 0; mt < 4; ++mt) {
                int addr = (mt * 16 + lane15) * LDK + kb * 32 + quad * 8;
                ah[mt] = *(const short8*)&Ahi[addr];
                al[mt] = *(const short8*)&Alo[addr];
            }
            short8 bh[NT], bl[NT];
#pragma unroll
            for (int nt = 0; nt < NT; ++nt) {
                int t = wave * NT + nt;
                size_t fb = ((size_t)(t * KB + kbg) * 64 + lane) * 8;
                bh[nt] = *(const short8*)&Whi[fb];
                bl[nt] = *(const short8*)&Wlo[fb];
            }
#pragma unroll
            for (int mt = 0; mt < 4; ++mt)
#pragma unroll
                for (int nt = 0; nt < NT; ++nt) {
                    acc[mt][nt] = __builtin_amdgcn_mfma_f32_16x16x32_bf16(ah[mt], bh[nt], acc[mt][nt], 0, 0, 0);
                    acc[mt][nt] = __builtin_amdgcn_mfma_f32_16x16x32_bf16(ah[mt], bl[nt], acc[mt][nt], 0, 0, 0);
                    acc[mt][nt] = __builtin_amdgcn_mfma_f32_16x16x32_bf16(al[mt], bh[nt], acc[mt][nt], 0, 0, 0);
                }
        }
    }

#pragma unroll
    for (int mt = 0; mt < 4; ++mt) {
#pragma unroll
        for (int nt = 0; nt < NT; ++nt) {
            int col = wave * (NT * 16) + nt * 16 + lane15;
            float bj = BIAS ? b[col] : 0.f;
#pragma unroll
            for (int reg = 0; reg < 4; ++reg) {
                int row = row0 + mt * 16 + quad * 4 + reg;
                if (row < n) {
                    float v = acc[mt][nt][reg] + bj;
                    if (RELU) v = fmaxf(v, 0.f);
                    if (SCALE) v *= sc[row];
                    if (OUTBF) ((unsigned short*)Hout)[(size_t)row * D + col] = f2b(v);
                    else       ((float*)Hout)[(size_t)row * D + col] = v;
                }
            }
        }
    }
}

// ---------------- readout: one block per graph, atomic-free mean ----------------
__global__ void graph_mean(const int* __restrict__ bstart, const float* __restrict__ X,
                           float* __restrict__ out) {
    int g = blockIdx.x;
    int r0 = bstart[g], r1 = bstart[g + 1];
    int col = threadIdx.x & 127, rr = threadIdx.x >> 7;  // 2 rows in flight
    float acc = 0.f;
    for (int r = r0 + rr; r < r1; r += 2)
        acc += X[(size_t)r * OUT_D + col];
    __shared__ float sh[128];
    if (rr == 1) sh[col] = acc;
    __syncthreads();
    if (rr == 0) {
        float tot = acc + sh[col];
        int c = r1 - r0;
        out[(size_t)g * OUT_D + col] = tot / (float)(c > 0 ? c : 1);
    }
}

extern "C" void kernel_launch(void* const* d_in, const int* in_sizes, int n_in,
                              void* d_out, int out_size, void* d_ws, size_t ws_size,
                              hipStream_t stream) {
    const int* node_ids = (const int*)d_in[0];
    const int* edge_index = (const int*)d_in[1];
    const int* batch = (const int*)d_in[2];
    const float* embed = (const float*)d_in[3];
    const float* W_in  = (const float*)d_in[4];
    const float* b_in  = (const float*)d_in[5];
    const float* W_h1  = (const float*)d_in[6];
    const float* b_h1  = (const float*)d_in[7];
    const float* W_h2  = (const float*)d_in[8];
    const float* b_h2  = (const float*)d_in[9];
    const float* W_out = (const float*)d_in[10];
    const float* b_out = (const float*)d_in[11];
    float* out = (float*)d_out;

    const int* src = edge_index;
    const int* dst = edge_index + N_EDGES;

    char* w = (char*)d_ws;
    size_t o = 0;
    auto alloc = [&](size_t bytes) -> void* {
        void* p = w + o;
        o = (o + bytes + 255) & ~(size_t)255;
        return p;
    };
    int*   deg8     = (int*)alloc((size_t)NSHARD * N_NODES * sizeof(int));
    int*   sb8      = (int*)alloc((size_t)NSHARD * N_NODES * sizeof(int));
    int*   degt     = (int*)alloc((size_t)N_NODES * sizeof(int));
    int*   pos      = (int*)alloc((size_t)N_EDGES * sizeof(int));
    float* dinv     = (float*)alloc((size_t)N_NODES * sizeof(float));
    int*   bstart   = (int*)alloc((size_t)(NGRAPH + 1) * sizeof(int));
    int*   row_start= (int*)alloc((size_t)(N_NODES + 1) * sizeof(int));
    int*   bsum     = (int*)alloc((size_t)SCAN_B * sizeof(int));
    int*   boff     = (int*)alloc((size_t)SCAN_B * sizeof(int));
    int*   csr_src  = (int*)alloc((size_t)N_EDGES * sizeof(int));
    float* X        = (float*)alloc((size_t)N_NODES * HID_D * sizeof(float));     // fp32 residual
    unsigned short* H16 = (unsigned short*)alloc((size_t)N_NODES * HID_D * sizeof(short)); // pre-scaled bf16
    float* A1       = (float*)alloc((size_t)N_NODES * 128 * sizeof(float));       // fp32 agg out (128-d)
    short* Whi_in   = (short*)alloc((size_t)EMB_D * HID_D * sizeof(short));
    short* Wlo_in   = (short*)alloc((size_t)EMB_D * HID_D * sizeof(short));
    short* Whi_h1   = (short*)alloc((size_t)HID_D * HID_D * sizeof(short));
    short* Wlo_h1   = (short*)alloc((size_t)HID_D * HID_D * sizeof(short));
    short* Whi_h2   = (short*)alloc((size_t)HID_D * HID_D * sizeof(short));
    short* Wlo_h2   = (short*)alloc((size_t)HID_D * HID_D * sizeof(short));
    short* Whi_out  = (short*)alloc((size_t)HID_D * OUT_D * sizeof(short));
    short* Wlo_out  = (short*)alloc((size_t)HID_D * OUT_D * sizeof(short));
    unsigned short* E16 = H16;               // layer-1 bf16 embeddings alias
    unsigned short* H4  = H16;               // layer-4 bf16 GEMM out [N,128] alias
    (void)ws_size;

    hipMemsetAsync(deg8, 0, (size_t)NSHARD * N_NODES * sizeof(int), stream);

    rank_kernel<<<(N_EDGES + 255) / 256, 256, 0, stream>>>(dst, deg8, pos);
    bstart_kernel<<<1, 512, 0, stream>>>(batch, bstart);
    scan_a<<<SCAN_B, 256, 0, stream>>>(deg8, degt, sb8, bsum, dinv);
    scan_b<<<1, 256, 0, stream>>>(bsum, boff);
    scan_c<<<SCAN_B, 256, 0, stream>>>(degt, boff, row_start);
    scatter_kernel<<<(N_EDGES + 255) / 256, 256, 0, stream>>>(src, dst, pos, row_start,
                                                              sb8, csr_src);

    wsplit_k<EMB_D, HID_D><<<(EMB_D * HID_D + 255) / 256, 256, 0, stream>>>(W_in, Whi_in, Wlo_in);
    wsplit_k<HID_D, HID_D><<<(HID_D * HID_D + 255) / 256, 256, 0, stream>>>(W_h1, Whi_h1, Wlo_h1);
    wsplit_k<HID_D, HID_D><<<(HID_D * HID_D + 255) / 256, 256, 0, stream>>>(W_h2, Whi_h2, Wlo_h2);
    wsplit_k<HID_D, OUT_D><<<(HID_D * OUT_D + 255) / 256, 256, 0, stream>>>(W_out, Whi_out, Wlo_out);

    const int gemm_grid = (N_NODES + 63) / 64;
    const int agg_grid = (N_NODES + 3) / 4;

    // ---- Layer 1: gather emb (pre-scaled bf16), agg at 128, GEMM 128->256 +bias+relu ----
    gather_bf16<<<(N_NODES * (EMB_D / 4) + 255) / 256, 256, 0, stream>>>(node_ids, embed, dinv, E16);
    agg_node<128, false, false, false><<<agg_grid, 256, 0, stream>>>(
        row_start, csr_src, dinv, E16, nullptr, A1);
    gemm_mfma<128, 256, true, true, false, false><<<gemm_grid, 256, 0, stream>>>(
        A1, Whi_in, Wlo_in, b_in, nullptr, X, N_NODES);

    // ---- Layer 2: GEMM 256->256 (bf16 out, row-scaled), fused agg+self+bias+res+relu ----
    gemm_mfma<256, 256, false, false, true, true><<<gemm_grid, 256, 0, stream>>>(
        X, Whi_h1, Wlo_h1, nullptr, dinv, H16, N_NODES);
    agg_node<256, true, true, true><<<agg_grid, 256, 0, stream>>>(
        row_start, csr_src, dinv, H16, b_h1, X);

    // ---- Layer 3: same ----
    gemm_mfma<256, 256, false, false, true, true><<<gemm_grid, 256, 0, stream>>>(
        X, Whi_h2, Wlo_h2, nullptr, dinv, H16, N_NODES);
    agg_node<256, true, true, true><<<agg_grid, 256, 0, stream>>>(
        row_start, csr_src, dinv, H16, b_h2, X);

    // ---- Layer 4: GEMM 256->128 (bf16 out, row-scaled), agg at 128 +bias ----
    gemm_mfma<256, 128, false, false, true, true><<<gemm_grid, 256, 0, stream>>>(
        X, Whi_out, Wlo_out, nullptr, dinv, H4, N_NODES);
    agg_node<128, true, false, false><<<agg_grid, 256, 0, stream>>>(
        row_start, csr_src, dinv, H4, b_out, A1);

    // ---- readout: atomic-free per-graph mean (batch sorted) ----
    graph_mean<<<NGRAPH, 256, 0, stream>>>(bstart, A1, out);
}